// Round 8
// baseline (204.988 us; speedup 1.0000x reference)
//
#include <hip/hip_runtime.h>

// ---------------------------------------------------------------------------
// Attention_25151328485403 — f16 MFMA path, round 8
//   prep:  converts (x->f16; W_qkv -> [N][K] q-cols ×0.125*log2e; W_out)
//   g1  :  qk = x_h @ Wqkv^T (cols<2048 compact [row][2048]); V-cols -> vt^T
//   at  :  flash attn, q=32/wave + 2-way KEY SPLIT (additive since no running
//          max): grid 16x32x2 = 1024 blocks (4/CU). Unnormalized f16 O + l out.
//   comb:  out = (O0+O1)/(l0+l1), q-mask applied
//   g2  :  out = aout_h @ Wout^T  (fp32)
// Lessons: R5 q=32 alone kills grid occupancy -> key-split restores it.
//          R6 vmcnt in-order: loop touches global ONLY via global_load_lds.
//          Attn is LDS-pipe-bound: amortize K/V frags over 2x queries.
// ---------------------------------------------------------------------------

typedef _Float16 half_t;
typedef __attribute__((ext_vector_type(8))) _Float16 half8;
typedef __attribute__((ext_vector_type(4))) _Float16 half4;
typedef __attribute__((ext_vector_type(4))) float floatx4;

#define SEQ 2048
#define DIM 1024
#define INNER 1024
#define NH 16
#define DH 64
#define BROWS 4096

__device__ inline void async16(const half_t* g, half_t* l) {
    __builtin_amdgcn_global_load_lds(
        (const __attribute__((address_space(1))) void*)g,
        (__attribute__((address_space(3))) void*)l, 16, 0, 0);
}

// ------------------------- fused prep (all converts) -----------------------
__global__ __launch_bounds__(256) void prep(const float* __restrict__ x,
                                            const float* __restrict__ Wqkv,
                                            const float* __restrict__ Wout,
                                            half_t* __restrict__ x_h,
                                            half_t* __restrict__ Wqkv_t,
                                            half_t* __restrict__ Wout_t) {
    __shared__ float tile[32][33];
    const int bid = blockIdx.x;
    const int tid = threadIdx.x;

    if (bid < 2048) {
        int i = (bid * 256 + tid) * 8;
        float4 v0 = *(const float4*)(x + i);
        float4 v1 = *(const float4*)(x + i + 4);
        half_t h[8];
        h[0] = (half_t)v0.x; h[1] = (half_t)v0.y; h[2] = (half_t)v0.z; h[3] = (half_t)v0.w;
        h[4] = (half_t)v1.x; h[5] = (half_t)v1.y; h[6] = (half_t)v1.z; h[7] = (half_t)v1.w;
        *(half8*)(x_h + i) = *(half8*)h;
        return;
    }

    const float* in;
    half_t* out;
    int R, C, scaleRows, c0, r0;
    float scale;
    if (bid < 5120) {
        int idx = bid - 2048;                 // W_qkv: 96 x 32 tiles
        in = Wqkv; out = Wqkv_t; R = DIM; C = 3 * INNER;
        scaleRows = INNER; scale = 0.1803368801111f;   // 0.125 * log2(e)
        c0 = (idx % 96) * 32; r0 = (idx / 96) * 32;
    } else {
        int idx = bid - 5120;                 // W_out: 32 x 32 tiles
        in = Wout; out = Wout_t; R = INNER; C = DIM;
        scaleRows = 0; scale = 1.0f;
        c0 = (idx % 32) * 32; r0 = (idx / 32) * 32;
    }
    const int tx = tid & 31, ty = tid >> 5;
#pragma unroll
    for (int i = 0; i < 32; i += 8)
        tile[ty + i][tx] = in[(size_t)(r0 + ty + i) * C + c0 + tx];
    __syncthreads();
#pragma unroll
    for (int i = 0; i < 32; i += 8) {
        int oc = c0 + ty + i;
        float s = (oc < scaleRows) ? scale : 1.0f;
        out[(size_t)oc * R + r0 + tx] = (half_t)(tile[tx][ty + i] * s);
    }
}

// ------------------------------ mfma GEMM ----------------------------------
// C = A[M,K] * B^T (B stored [N][K]).  MODE 0: f32 C[M,N].  MODE 2: qkv —
// cols<2048 -> qk [row][2048] f16; cols>=2048 -> vt [bh][64 d][2048 seq].
template <int MODE, int WMT, int WNT>
__global__ __launch_bounds__(256) void gemm_f16_bt(const half_t* __restrict__ A,
                                                   const half_t* __restrict__ B,
                                                   void* __restrict__ Cout,
                                                   half_t* __restrict__ vt,
                                                   int M, int N, int K) {
    constexpr int BM = 32 * WMT;
    constexpr int BN = 32 * WNT;
    __shared__ half_t As[BM * 64];
    __shared__ half_t Bs[BN * 64];
    const int tid = threadIdx.x;
    const int wave = tid >> 6;
    const int lane = tid & 63;
    const int l15 = lane & 15;
    const int quad = lane >> 4;
    const int m0 = blockIdx.y * BM;
    const int n0 = blockIdx.x * BN;
    const int wm = (wave & 1) * (16 * WMT);
    const int wn = (wave >> 1) * (16 * WNT);

    floatx4 acc[WMT][WNT];
#pragma unroll
    for (int i = 0; i < WMT; ++i)
#pragma unroll
        for (int j = 0; j < WNT; ++j) acc[i][j] = (floatx4){0.f, 0.f, 0.f, 0.f};

    for (int k0 = 0; k0 < K; k0 += 64) {
        __syncthreads();
#pragma unroll
        for (int i = 0; i < BM * 8 / 256; ++i) {
            int chunk = i * 256 + tid;
            int row = chunk >> 3, c = chunk & 7;
            int gc = c ^ (row & 7);
            async16(A + (size_t)(m0 + row) * K + k0 + gc * 8, As + chunk * 8);
        }
#pragma unroll
        for (int i = 0; i < BN * 8 / 256; ++i) {
            int chunk = i * 256 + tid;
            int row = chunk >> 3, c = chunk & 7;
            int gc = c ^ (row & 7);
            async16(B + (size_t)(n0 + row) * K + k0 + gc * 8, Bs + chunk * 8);
        }
        __syncthreads();
#pragma unroll
        for (int ks = 0; ks < 2; ++ks) {
            const int g = ks * 4 + quad;
            half8 af[WMT], bf[WNT];
#pragma unroll
            for (int i = 0; i < WMT; ++i) {
                int m = wm + i * 16 + l15;
                af[i] = *(const half8*)(As + m * 64 + (g ^ (m & 7)) * 8);
            }
#pragma unroll
            for (int j = 0; j < WNT; ++j) {
                int n = wn + j * 16 + l15;
                bf[j] = *(const half8*)(Bs + n * 64 + (g ^ (n & 7)) * 8);
            }
#pragma unroll
            for (int i = 0; i < WMT; ++i)
#pragma unroll
                for (int j = 0; j < WNT; ++j)
                    acc[i][j] = __builtin_amdgcn_mfma_f32_16x16x32_f16(af[i], bf[j],
                                                                       acc[i][j], 0, 0, 0);
        }
    }

    if (MODE == 2 && n0 >= 2 * INNER) {
        // V block: write transposed to vt[bh][d][seq] as half4 along seq
#pragma unroll
        for (int i = 0; i < WMT; ++i) {
            int row0 = m0 + wm + i * 16 + quad * 4;
            int seq0 = row0 & (SEQ - 1);
            int bhb = (row0 >> 11) << 4;           // b * 16
#pragma unroll
            for (int j = 0; j < WNT; ++j) {
                int vc = n0 + wn + j * 16 + l15 - 2 * INNER;   // h*64 + d
                half4 v4;
#pragma unroll
                for (int r = 0; r < 4; ++r) v4[r] = (half_t)acc[i][j][r];
                *(half4*)(vt + ((size_t)(bhb + (vc >> 6)) * DH + (vc & 63)) * SEQ +
                          seq0) = v4;
            }
        }
        return;
    }

#pragma unroll
    for (int i = 0; i < WMT; ++i)
#pragma unroll
        for (int j = 0; j < WNT; ++j)
#pragma unroll
            for (int r = 0; r < 4; ++r) {
                size_t row = m0 + wm + i * 16 + quad * 4 + r;
                size_t col = n0 + wn + j * 16 + l15;
                if (MODE == 2)
                    ((half_t*)Cout)[row * 2048 + col] = (half_t)acc[i][j][r];
                else
                    ((float*)Cout)[row * N + col] = acc[i][j][r];
            }
}

// ------------------------------ attention ----------------------------------
// 256 thr = 4 waves; 128 q/block (32/wave); 2-way key split via blockIdx.z
// (additive: no running max). K-tiles of 64, single buffer, 2 barriers/tile.
// Block's half-mask LDS-resident -> loop global traffic = global_load_lds only.
// Outputs UNNORMALIZED O (f16) + per-q l; combine kernel finishes.
__global__ __launch_bounds__(256, 4) void attn_mfma(const half_t* __restrict__ qk,
                                                    const half_t* __restrict__ vt,
                                                    const float* __restrict__ mask,
                                                    half_t* __restrict__ O0,
                                                    half_t* __restrict__ O1,
                                                    float* __restrict__ l_ws) {
    __shared__ half_t Ks[64 * 64];        // [key][d], chunks xor-swizzled
    __shared__ half_t Vs[64 * 64];        // [d][key], chunks xor-swizzled
    __shared__ half_t Ps[4][32 * 64];     // per-wave [q][key], chunks xor-swizzled
    __shared__ float smask[1024];         // this key-half's mask

    const int tid = threadIdx.x;
    const int wave = tid >> 6;
    const int lane = tid & 63;
    const int l15 = lane & 15;
    const int quad = lane >> 4;
    const int sw = l15 & 7;
    const int bh = blockIdx.y;
    const int b = bh >> 4, h = bh & 15;
    const int qi0 = blockIdx.x * 128;
    const int kh = blockIdx.z;            // key half: keys [kh*1024, kh*1024+1024)

    // stage this half's mask row (256 float4)
    ((float4*)smask)[tid] = ((const float4*)(mask + (size_t)b * SEQ + kh * 1024))[tid];

    // Q fragments from global (0.125*log2e folded into W_qkv q-cols)
    const half_t* qrow0 = qk + (size_t)(b * SEQ + qi0 + wave * 32 + l15) * 2048 + h * DH;
    const half_t* qrow1 = qrow0 + (size_t)16 * 2048;
    half8 qf[2][2];
    qf[0][0] = *(const half8*)(qrow0 + quad * 8);
    qf[0][1] = *(const half8*)(qrow0 + 32 + quad * 8);
    qf[1][0] = *(const half8*)(qrow1 + quad * 8);
    qf[1][1] = *(const half8*)(qrow1 + 32 + quad * 8);

    const half_t* kbase0 = qk + (size_t)b * SEQ * 2048 + INNER + h * DH;
    const half_t* vtb = vt + (size_t)bh * DH * SEQ;
    half_t* Psw = &Ps[wave][0];

    floatx4 accO[2][4];
#pragma unroll
    for (int hh = 0; hh < 2; ++hh)
#pragma unroll
        for (int nt = 0; nt < 4; ++nt) accO[hh][nt] = (floatx4){0.f, 0.f, 0.f, 0.f};
    float l_i[2] = {0.f, 0.f};

    for (int kt = 0; kt < 16; ++kt) {
        const int kjg = kh * 1024 + kt * 64;    // global key base
        const int kjl = kt * 64;                // local (smask) base
        __syncthreads();                  // prior tile's reads done
#pragma unroll
        for (int i = 0; i < 2; ++i) {
            int chunk = i * 256 + tid;
            int row = chunk >> 3, c = chunk & 7;
            int gc = c ^ (row & 7);
            async16(kbase0 + (size_t)(kjg + row) * 2048 + gc * 8, Ks + chunk * 8);
        }
#pragma unroll
        for (int i = 0; i < 2; ++i) {
            int chunk = i * 256 + tid;
            int row = chunk >> 3, c = chunk & 7;
            int gc = c ^ (row & 7);
            async16(vtb + (size_t)row * SEQ + kjg + gc * 8, Vs + chunk * 8);
        }
        __syncthreads();                  // staging landed (iter0: also smask)

        float4 kmv[4];
#pragma unroll
        for (int mt = 0; mt < 4; ++mt)
            kmv[mt] = *(const float4*)&smask[kjl + mt * 16 + quad * 4];

        // ---- S^T = K Q^T : rows = keys (mt*16+quad*4+r), cols = q (l15) ----
        floatx4 accS[2][4];
#pragma unroll
        for (int hh = 0; hh < 2; ++hh)
#pragma unroll
            for (int mt = 0; mt < 4; ++mt) accS[hh][mt] = (floatx4){0.f, 0.f, 0.f, 0.f};
#pragma unroll
        for (int ks = 0; ks < 2; ++ks) {
#pragma unroll
            for (int mt = 0; mt < 4; ++mt) {
                half8 af = *(const half8*)(Ks + (mt * 16 + l15) * 64 +
                                           ((ks * 4 + quad) ^ sw) * 8);
                accS[0][mt] = __builtin_amdgcn_mfma_f32_16x16x32_f16(af, qf[0][ks],
                                                                     accS[0][mt], 0, 0, 0);
                accS[1][mt] = __builtin_amdgcn_mfma_f32_16x16x32_f16(af, qf[1][ks],
                                                                     accS[1][mt], 0, 0, 0);
            }
        }

        // ---- p = km * 2^s ; deferred l ----
#pragma unroll
        for (int hh = 0; hh < 2; ++hh)
#pragma unroll
            for (int mt = 0; mt < 4; ++mt) {
                float kmr[4] = {kmv[mt].x, kmv[mt].y, kmv[mt].z, kmv[mt].w};
                half4 p4;
#pragma unroll
                for (int r = 0; r < 4; ++r) {
                    float p = kmr[r] * __builtin_amdgcn_exp2f(accS[hh][mt][r]);
                    l_i[hh] += p;
                    p4[r] = (half_t)p;
                }
                int cw = mt * 2 + (quad >> 1);
                *(half4*)(Psw + (hh * 16 + l15) * 64 +
                          ((cw ^ sw) * 8 + (quad & 1) * 4)) = p4;
            }

        // ---- O += P V ----
#pragma unroll
        for (int ks2 = 0; ks2 < 2; ++ks2) {
            const int ko = ((ks2 * 4 + quad) ^ sw) * 8;
            half8 pf0 = *(const half8*)(Psw + l15 * 64 + ko);
            half8 pf1 = *(const half8*)(Psw + (16 + l15) * 64 + ko);
#pragma unroll
            for (int nt = 0; nt < 4; ++nt) {
                half8 vf = *(const half8*)(Vs + (nt * 16 + l15) * 64 + ko);
                accO[0][nt] = __builtin_amdgcn_mfma_f32_16x16x32_f16(pf0, vf,
                                                                     accO[0][nt], 0, 0, 0);
                accO[1][nt] = __builtin_amdgcn_mfma_f32_16x16x32_f16(pf1, vf,
                                                                     accO[1][nt], 0, 0, 0);
            }
        }
    }

    // l: reduce across quads, write per-q (quad 0 lanes)
#pragma unroll
    for (int hh = 0; hh < 2; ++hh) {
        l_i[hh] += __shfl_xor(l_i[hh], 16, 64);
        l_i[hh] += __shfl_xor(l_i[hh], 32, 64);
    }
    float* lw = l_ws + (size_t)kh * 65536 + (size_t)bh * SEQ + qi0 + wave * 32;
    if (quad == 0) {
        lw[l15] = l_i[0];
        lw[16 + l15] = l_i[1];
    }

    // unnormalized O (f16) to this half's buffer
    half_t* obuf = (kh == 0) ? O0 : O1;
#pragma unroll
    for (int hh = 0; hh < 2; ++hh)
#pragma unroll
        for (int nt = 0; nt < 4; ++nt)
#pragma unroll
            for (int r = 0; r < 4; ++r) {
                size_t row = (size_t)(b * SEQ + qi0 + wave * 32 + hh * 16 + quad * 4 + r);
                obuf[row * INNER + h * DH + nt * 16 + l15] = (half_t)accO[hh][nt][r];
            }
}

// ------------------------------ combine ------------------------------------
// aout (=O1 buffer) <- (O0 + O1) / (l0 + l1), zeroed where q masked out
__global__ __launch_bounds__(256) void combine(const half_t* __restrict__ O0,
                                               half_t* __restrict__ O1,
                                               const float* __restrict__ l_ws,
                                               const float* __restrict__ mask) {
    const int idx = blockIdx.x * 256 + threadIdx.x;
    const int base = idx * 8;
    const int row = base >> 10;           // [0, 4096)
    const int col = base & 1023;
    const int b = row >> 11;
    const int q = row & 2047;
    const int bh = b * 16 + (col >> 6);
    const float l = l_ws[(size_t)bh * SEQ + q] + l_ws[65536 + (size_t)bh * SEQ + q];
    const float qm = mask[row];
    const float inv = (qm > 0.5f && l > 0.f) ? 1.0f / l : 0.f;
    half8 a = *(const half8*)(O0 + base);
    half8 c = *(const half8*)(O1 + base);
    half8 o;
#pragma unroll
    for (int k = 0; k < 8; ++k) o[k] = (half_t)(((float)a[k] + (float)c[k]) * inv);
    *(half8*)(O1 + base) = o;
}

// ------------------------------- launch ------------------------------------
extern "C" void kernel_launch(void* const* d_in, const int* in_sizes, int n_in,
                              void* d_out, int out_size, void* d_ws, size_t ws_size,
                              hipStream_t stream) {
    const float* x    = (const float*)d_in[0];
    const float* mask = (const float*)d_in[1];
    const float* Wqkv = (const float*)d_in[2];   // [1024][3072]
    const float* Wout = (const float*)d_in[3];   // [1024][1024]
    float* out = (float*)d_out;

    // halves layout (Mi halves): x_h/O0 [0,4), Wqkv_t [4,7), Wout_t [7,8),
    // qk [8,16), vt [16,20), aout/O1 [20,24), l_ws @48MB (512KB)
    half_t* x_h    = (half_t*)d_ws;
    half_t* Wqkv_t = x_h + (size_t)4 * 1024 * 1024;
    half_t* Wout_t = Wqkv_t + (size_t)3 * 1024 * 1024;
    half_t* qk     = Wout_t + (size_t)1024 * 1024;        // [4096][2048]
    half_t* vt     = qk + (size_t)8 * 1024 * 1024;        // [32][64][2048]
    half_t* aout_h = vt + (size_t)4 * 1024 * 1024;        // [4096][1024] = O1
    float*  l_ws   = (float*)(aout_h + (size_t)4 * 1024 * 1024);  // 2*32*2048
    half_t* O0     = x_h;                                 // x_h dead after g1

    prep<<<6144, 256, 0, stream>>>(x, Wqkv, Wout, x_h, Wqkv_t, Wout_t);

    // qkv projection: q,k -> qk compact; V -> vt transposed
    gemm_f16_bt<2, 4, 4><<<dim3(3 * INNER / 128, BROWS / 128), 256, 0, stream>>>(
        x_h, Wqkv_t, qk, vt, BROWS, 3 * INNER, DIM);

    attn_mfma<<<dim3(SEQ / 128, 2 * NH, 2), 256, 0, stream>>>(
        qk, vt, mask, O0, aout_h, l_ws);

    combine<<<2048, 256, 0, stream>>>(O0, aout_h, l_ws, mask);

    // output projection, 64x128 tile -> 512 blocks (2/CU)
    gemm_f16_bt<0, 2, 4><<<dim3(DIM / 128, BROWS / 64), 256, 0, stream>>>(
        aout_h, Wout_t, out, nullptr, BROWS, DIM, INNER);
}

// Round 9
// 183.054 us; speedup vs baseline: 1.1198x; 1.1198x over previous
//
#include <hip/hip_runtime.h>

// ---------------------------------------------------------------------------
// Attention_25151328485403 — f16 MFMA path, round 9
//   prep:  converts (x->f16; W_qkv -> [N][K] q-cols ×0.125*log2e; W_out) +
//          per-batch masked-key counts
//   g1  :  qkv = x_h @ Wqkv^T, ALL rows ×mask[row] (exact 0/1): masked K rows
//          -> s=0 -> p=1, masked V rows -> PV adds 0; l fixed in combine.
//          q,k -> qk compact [row][2048]; V -> vt transposed [bh][64][2048]
//   at  :  flash attn, 32 q/wave, 2-way key split, MASK-FREE memory-quiet
//          K-loop, double-buffered K/V (one barrier/tile), Ps chunked 8 KB,
//          LDS 40 KB -> 4 blocks/CU. Unnormalized f16 O + l out.
//   comb:  out = (O0+O1)/(l0+l1-#masked(b)), q-mask applied
//   g2  :  out = aout_h @ Wout^T  (fp32)
// Lessons: R5 q=32 alone kills grid; R6 any global read in loop defeats dbuf
// (vmcnt in-order); R8 loop is latency-bound once VALU shrinks -> hide with
// dbuf + fully memory-quiet loop.
// ---------------------------------------------------------------------------

typedef _Float16 half_t;
typedef __attribute__((ext_vector_type(8))) _Float16 half8;
typedef __attribute__((ext_vector_type(4))) _Float16 half4;
typedef __attribute__((ext_vector_type(4))) float floatx4;

#define SEQ 2048
#define DIM 1024
#define INNER 1024
#define NH 16
#define DH 64
#define BROWS 4096

__device__ inline void async16(const half_t* g, half_t* l) {
    __builtin_amdgcn_global_load_lds(
        (const __attribute__((address_space(1))) void*)g,
        (__attribute__((address_space(3))) void*)l, 16, 0, 0);
}

// ------------------- fused prep (converts + mask counts) -------------------
__global__ __launch_bounds__(256) void prep(const float* __restrict__ x,
                                            const float* __restrict__ Wqkv,
                                            const float* __restrict__ Wout,
                                            const float* __restrict__ mask,
                                            half_t* __restrict__ x_h,
                                            half_t* __restrict__ Wqkv_t,
                                            half_t* __restrict__ Wout_t,
                                            float* __restrict__ mc) {
    __shared__ float tile[32][33];
    const int bid = blockIdx.x;
    const int tid = threadIdx.x;

    if (bid < 2048) {
        int i = (bid * 256 + tid) * 8;
        float4 v0 = *(const float4*)(x + i);
        float4 v1 = *(const float4*)(x + i + 4);
        half_t h[8];
        h[0] = (half_t)v0.x; h[1] = (half_t)v0.y; h[2] = (half_t)v0.z; h[3] = (half_t)v0.w;
        h[4] = (half_t)v1.x; h[5] = (half_t)v1.y; h[6] = (half_t)v1.z; h[7] = (half_t)v1.w;
        *(half8*)(x_h + i) = *(half8*)h;
        return;
    }
    if (bid >= 6144) {                        // masked-key count for batch b
        int b = bid - 6144;
        float4 a = ((const float4*)(mask + (size_t)b * SEQ))[tid * 2];
        float4 c = ((const float4*)(mask + (size_t)b * SEQ))[tid * 2 + 1];
        float s = a.x + a.y + a.z + a.w + c.x + c.y + c.z + c.w;
#pragma unroll
        for (int off = 1; off < 64; off <<= 1) s += __shfl_xor(s, off, 64);
        float* red = &tile[0][0];
        if ((tid & 63) == 0) red[tid >> 6] = s;
        __syncthreads();
        if (tid == 0) mc[b] = (float)SEQ - (red[0] + red[1] + red[2] + red[3]);
        return;
    }

    const float* in;
    half_t* out;
    int R, C, scaleRows, c0, r0;
    float scale;
    if (bid < 5120) {
        int idx = bid - 2048;                 // W_qkv: 96 x 32 tiles
        in = Wqkv; out = Wqkv_t; R = DIM; C = 3 * INNER;
        scaleRows = INNER; scale = 0.1803368801111f;   // 0.125 * log2(e)
        c0 = (idx % 96) * 32; r0 = (idx / 96) * 32;
    } else {
        int idx = bid - 5120;                 // W_out: 32 x 32 tiles
        in = Wout; out = Wout_t; R = INNER; C = DIM;
        scaleRows = 0; scale = 1.0f;
        c0 = (idx % 32) * 32; r0 = (idx / 32) * 32;
    }
    const int tx = tid & 31, ty = tid >> 5;
#pragma unroll
    for (int i = 0; i < 32; i += 8)
        tile[ty + i][tx] = in[(size_t)(r0 + ty + i) * C + c0 + tx];
    __syncthreads();
#pragma unroll
    for (int i = 0; i < 32; i += 8) {
        int oc = c0 + ty + i;
        float s = (oc < scaleRows) ? scale : 1.0f;
        out[(size_t)oc * R + r0 + tx] = (half_t)(tile[tx][ty + i] * s);
    }
}

// ------------------------------ mfma GEMM ----------------------------------
// MODE 0: f32 C[M,N].  MODE 2: qkv — rows scaled by mask[row]; cols<2048 ->
// qk [row][2048] f16; cols>=2048 -> vt [bh][64 d][2048 seq] transposed.
template <int MODE, int WMT, int WNT>
__global__ __launch_bounds__(256) void gemm_f16_bt(const half_t* __restrict__ A,
                                                   const half_t* __restrict__ B,
                                                   void* __restrict__ Cout,
                                                   half_t* __restrict__ vt,
                                                   const float* __restrict__ mask,
                                                   int M, int N, int K) {
    constexpr int BM = 32 * WMT;
    constexpr int BN = 32 * WNT;
    __shared__ half_t As[BM * 64];
    __shared__ half_t Bs[BN * 64];
    const int tid = threadIdx.x;
    const int wave = tid >> 6;
    const int lane = tid & 63;
    const int l15 = lane & 15;
    const int quad = lane >> 4;
    const int m0 = blockIdx.y * BM;
    const int n0 = blockIdx.x * BN;
    const int wm = (wave & 1) * (16 * WMT);
    const int wn = (wave >> 1) * (16 * WNT);

    floatx4 acc[WMT][WNT];
#pragma unroll
    for (int i = 0; i < WMT; ++i)
#pragma unroll
        for (int j = 0; j < WNT; ++j) acc[i][j] = (floatx4){0.f, 0.f, 0.f, 0.f};

    for (int k0 = 0; k0 < K; k0 += 64) {
        __syncthreads();
#pragma unroll
        for (int i = 0; i < BM * 8 / 256; ++i) {
            int chunk = i * 256 + tid;
            int row = chunk >> 3, c = chunk & 7;
            int gc = c ^ (row & 7);
            async16(A + (size_t)(m0 + row) * K + k0 + gc * 8, As + chunk * 8);
        }
#pragma unroll
        for (int i = 0; i < BN * 8 / 256; ++i) {
            int chunk = i * 256 + tid;
            int row = chunk >> 3, c = chunk & 7;
            int gc = c ^ (row & 7);
            async16(B + (size_t)(n0 + row) * K + k0 + gc * 8, Bs + chunk * 8);
        }
        __syncthreads();
#pragma unroll
        for (int ks = 0; ks < 2; ++ks) {
            const int g = ks * 4 + quad;
            half8 af[WMT], bf[WNT];
#pragma unroll
            for (int i = 0; i < WMT; ++i) {
                int m = wm + i * 16 + l15;
                af[i] = *(const half8*)(As + m * 64 + (g ^ (m & 7)) * 8);
            }
#pragma unroll
            for (int j = 0; j < WNT; ++j) {
                int n = wn + j * 16 + l15;
                bf[j] = *(const half8*)(Bs + n * 64 + (g ^ (n & 7)) * 8);
            }
#pragma unroll
            for (int i = 0; i < WMT; ++i)
#pragma unroll
                for (int j = 0; j < WNT; ++j)
                    acc[i][j] = __builtin_amdgcn_mfma_f32_16x16x32_f16(af[i], bf[j],
                                                                       acc[i][j], 0, 0, 0);
        }
    }

    if (MODE == 2) {
        // scale all rows by mask (exact 0/1): masked K -> s=0, masked V -> 0
#pragma unroll
        for (int i = 0; i < WMT; ++i) {
            int row0 = m0 + wm + i * 16 + quad * 4;
            float4 mv = *(const float4*)(mask + row0);
            float mvr[4] = {mv.x, mv.y, mv.z, mv.w};
            if (n0 >= 2 * INNER) {            // V block -> vt transposed
                int seq0 = row0 & (SEQ - 1);
                int bhb = (row0 >> 11) << 4;
#pragma unroll
                for (int j = 0; j < WNT; ++j) {
                    int vc = n0 + wn + j * 16 + l15 - 2 * INNER;
                    half4 v4;
#pragma unroll
                    for (int r = 0; r < 4; ++r) v4[r] = (half_t)(acc[i][j][r] * mvr[r]);
                    *(half4*)(vt + ((size_t)(bhb + (vc >> 6)) * DH + (vc & 63)) * SEQ +
                              seq0) = v4;
                }
            } else {                          // q/k block -> compact qk
#pragma unroll
                for (int j = 0; j < WNT; ++j) {
                    size_t col = n0 + wn + j * 16 + l15;
#pragma unroll
                    for (int r = 0; r < 4; ++r)
                        ((half_t*)Cout)[(size_t)(row0 + r) * 2048 + col] =
                            (half_t)(acc[i][j][r] * mvr[r]);
                }
            }
        }
        return;
    }

#pragma unroll
    for (int i = 0; i < WMT; ++i)
#pragma unroll
        for (int j = 0; j < WNT; ++j)
#pragma unroll
            for (int r = 0; r < 4; ++r) {
                size_t row = m0 + wm + i * 16 + quad * 4 + r;
                size_t col = n0 + wn + j * 16 + l15;
                ((float*)Cout)[row * N + col] = acc[i][j][r];
            }
}

// ------------------------------ attention ----------------------------------
// 256 thr = 4 waves; 128 q/block (32/wave); 2-way key split (blockIdx.z).
// Double-buffered K/V, ONE barrier/tile, prefetch right after barrier.
// Inner loop touches NO global memory except global_load_lds (vmcnt-clean).
// No mask handling (pre-zeroed K/V rows; l corrected in combine).
__global__ __launch_bounds__(256, 4) void attn_mfma(const half_t* __restrict__ qk,
                                                    const half_t* __restrict__ vt,
                                                    half_t* __restrict__ O0,
                                                    half_t* __restrict__ O1,
                                                    float* __restrict__ l_ws) {
    __shared__ half_t Ks[2][64 * 64];     // [key][d], chunks xor-swizzled (16 KB)
    __shared__ half_t Vs[2][64 * 64];     // [d][key], chunks xor-swizzled (16 KB)
    __shared__ half_t Ps[4][32 * 32];     // per-wave [q][32-key chunk]     (8 KB)

    const int tid = threadIdx.x;
    const int wave = tid >> 6;
    const int lane = tid & 63;
    const int l15 = lane & 15;
    const int quad = lane >> 4;
    const int sw = l15 & 7;
    const int sw3 = l15 & 3;              // Ps chunk swizzle (32-half rows)
    const int bh = blockIdx.y;
    const int b = bh >> 4, h = bh & 15;
    const int qi0 = blockIdx.x * 128;
    const int kh = blockIdx.z;            // keys [kh*1024, kh*1024+1024)

    // Q fragments from global (0.125*log2e folded into W_qkv q-cols)
    const half_t* qrow0 = qk + (size_t)(b * SEQ + qi0 + wave * 32 + l15) * 2048 + h * DH;
    const half_t* qrow1 = qrow0 + (size_t)16 * 2048;
    half8 qf[2][2];
    qf[0][0] = *(const half8*)(qrow0 + quad * 8);
    qf[0][1] = *(const half8*)(qrow0 + 32 + quad * 8);
    qf[1][0] = *(const half8*)(qrow1 + quad * 8);
    qf[1][1] = *(const half8*)(qrow1 + 32 + quad * 8);

    const half_t* kbase0 = qk + (size_t)b * SEQ * 2048 + INNER + h * DH;
    const half_t* vtb = vt + (size_t)bh * DH * SEQ;
    half_t* Psw = &Ps[wave][0];

    floatx4 accO[2][4];
#pragma unroll
    for (int hh = 0; hh < 2; ++hh)
#pragma unroll
        for (int nt = 0; nt < 4; ++nt) accO[hh][nt] = (floatx4){0.f, 0.f, 0.f, 0.f};
    float l_i[2] = {0.f, 0.f};

    auto stage = [&](int kt, int buf) {
        const int kjg = kh * 1024 + kt * 64;
#pragma unroll
        for (int i = 0; i < 2; ++i) {
            int chunk = i * 256 + tid;
            int row = chunk >> 3, c = chunk & 7;
            int gc = c ^ (row & 7);
            async16(kbase0 + (size_t)(kjg + row) * 2048 + gc * 8, Ks[buf] + chunk * 8);
        }
#pragma unroll
        for (int i = 0; i < 2; ++i) {
            int chunk = i * 256 + tid;
            int row = chunk >> 3, c = chunk & 7;
            int gc = c ^ (row & 7);
            async16(vtb + (size_t)row * SEQ + kjg + gc * 8, Vs[buf] + chunk * 8);
        }
    };

    stage(0, 0);

    for (int kt = 0; kt < 16; ++kt) {
        const int buf = kt & 1;
        __syncthreads();                  // buf's loads drained; buf^1 reads done
        if (kt + 1 < 16) stage(kt + 1, buf ^ 1);   // ages a full tile

        // ---- S^T = K Q^T : rows = keys (mt*16+quad*4+r), cols = q (l15) ----
        floatx4 accS[2][4];
#pragma unroll
        for (int hh = 0; hh < 2; ++hh)
#pragma unroll
            for (int mt = 0; mt < 4; ++mt) accS[hh][mt] = (floatx4){0.f, 0.f, 0.f, 0.f};
#pragma unroll
        for (int ks = 0; ks < 2; ++ks) {
#pragma unroll
            for (int mt = 0; mt < 4; ++mt) {
                half8 af = *(const half8*)(Ks[buf] + (mt * 16 + l15) * 64 +
                                           ((ks * 4 + quad) ^ sw) * 8);
                accS[0][mt] = __builtin_amdgcn_mfma_f32_16x16x32_f16(af, qf[0][ks],
                                                                     accS[0][mt], 0, 0, 0);
                accS[1][mt] = __builtin_amdgcn_mfma_f32_16x16x32_f16(af, qf[1][ks],
                                                                     accS[1][mt], 0, 0, 0);
            }
        }

        // ---- p = 2^s (mask pre-applied via zeroed K/V); chunked PV ----
#pragma unroll
        for (int c = 0; c < 2; ++c) {
#pragma unroll
            for (int hh = 0; hh < 2; ++hh)
#pragma unroll
                for (int mtl = 0; mtl < 2; ++mtl) {
                    const int mt = c * 2 + mtl;
                    half4 p4;
#pragma unroll
                    for (int r = 0; r < 4; ++r) {
                        float p = __builtin_amdgcn_exp2f(accS[hh][mt][r]);
                        l_i[hh] += p;
                        p4[r] = (half_t)p;
                    }
                    int cw = (mtl * 2 + (quad >> 1)) ^ sw3;
                    *(half4*)(Psw + (hh * 16 + l15) * 32 + cw * 8 + (quad & 1) * 4) = p4;
                }
            const int rc = (quad ^ sw3) * 8;
            half8 pf0 = *(const half8*)(Psw + l15 * 32 + rc);
            half8 pf1 = *(const half8*)(Psw + (16 + l15) * 32 + rc);
            const int ko = ((c * 4 + quad) ^ sw) * 8;
#pragma unroll
            for (int nt = 0; nt < 4; ++nt) {
                half8 vf = *(const half8*)(Vs[buf] + (nt * 16 + l15) * 64 + ko);
                accO[0][nt] = __builtin_amdgcn_mfma_f32_16x16x32_f16(pf0, vf,
                                                                     accO[0][nt], 0, 0, 0);
                accO[1][nt] = __builtin_amdgcn_mfma_f32_16x16x32_f16(pf1, vf,
                                                                     accO[1][nt], 0, 0, 0);
            }
        }
    }

    // l: reduce across quads, write per-q
#pragma unroll
    for (int hh = 0; hh < 2; ++hh) {
        l_i[hh] += __shfl_xor(l_i[hh], 16, 64);
        l_i[hh] += __shfl_xor(l_i[hh], 32, 64);
    }
    float* lw = l_ws + (size_t)kh * 65536 + (size_t)bh * SEQ + qi0 + wave * 32;
    if (quad == 0) {
        lw[l15] = l_i[0];
        lw[16 + l15] = l_i[1];
    }

    half_t* obuf = (kh == 0) ? O0 : O1;
#pragma unroll
    for (int hh = 0; hh < 2; ++hh)
#pragma unroll
        for (int nt = 0; nt < 4; ++nt)
#pragma unroll
            for (int r = 0; r < 4; ++r) {
                size_t row = (size_t)(b * SEQ + qi0 + wave * 32 + hh * 16 + quad * 4 + r);
                obuf[row * INNER + h * DH + nt * 16 + l15] = (half_t)accO[hh][nt][r];
            }
}

// ------------------------------ combine ------------------------------------
// aout (=O1) <- (O0 + O1) / (l0 + l1 - #masked(b)), zeroed where q masked
__global__ __launch_bounds__(256) void combine(const half_t* __restrict__ O0,
                                               half_t* __restrict__ O1,
                                               const float* __restrict__ l_ws,
                                               const float* __restrict__ mask) {
    const int idx = blockIdx.x * 256 + threadIdx.x;
    const int base = idx * 8;
    const int row = base >> 10;           // [0, 4096)
    const int col = base & 1023;
    const int b = row >> 11;
    const int q = row & 2047;
    const int bh = b * 16 + (col >> 6);
    const float l = l_ws[(size_t)bh * SEQ + q] + l_ws[65536 + (size_t)bh * SEQ + q]
                  - l_ws[131072 + b];
    const float qm = mask[row];
    const float inv = (qm > 0.5f && l > 0.f) ? 1.0f / l : 0.f;
    half8 a = *(const half8*)(O0 + base);
    half8 c = *(const half8*)(O1 + base);
    half8 o;
#pragma unroll
    for (int k = 0; k < 8; ++k) o[k] = (half_t)(((float)a[k] + (float)c[k]) * inv);
    *(half8*)(O1 + base) = o;
}

// ------------------------------- launch ------------------------------------
extern "C" void kernel_launch(void* const* d_in, const int* in_sizes, int n_in,
                              void* d_out, int out_size, void* d_ws, size_t ws_size,
                              hipStream_t stream) {
    const float* x    = (const float*)d_in[0];
    const float* mask = (const float*)d_in[1];
    const float* Wqkv = (const float*)d_in[2];   // [1024][3072]
    const float* Wout = (const float*)d_in[3];   // [1024][1024]
    float* out = (float*)d_out;

    half_t* x_h    = (half_t*)d_ws;                       // also O0 after g1
    half_t* Wqkv_t = x_h + (size_t)4 * 1024 * 1024;
    half_t* Wout_t = Wqkv_t + (size_t)3 * 1024 * 1024;
    half_t* qk     = Wout_t + (size_t)1024 * 1024;        // [4096][2048]
    half_t* vt     = qk + (size_t)8 * 1024 * 1024;        // [32][64][2048]
    half_t* aout_h = vt + (size_t)4 * 1024 * 1024;        // [4096][1024] = O1
    float*  l_ws   = (float*)(aout_h + (size_t)4 * 1024 * 1024);  // 2*65536 + 2
    half_t* O0     = x_h;

    prep<<<6146, 256, 0, stream>>>(x, Wqkv, Wout, mask, x_h, Wqkv_t, Wout_t,
                                   l_ws + 131072);

    gemm_f16_bt<2, 4, 4><<<dim3(3 * INNER / 128, BROWS / 128), 256, 0, stream>>>(
        x_h, Wqkv_t, qk, vt, mask, BROWS, 3 * INNER, DIM);

    attn_mfma<<<dim3(SEQ / 128, 2 * NH, 2), 256, 0, stream>>>(
        qk, vt, O0, aout_h, l_ws);

    combine<<<2048, 256, 0, stream>>>(O0, aout_h, l_ws, mask);

    gemm_f16_bt<0, 2, 4><<<dim3(DIM / 128, BROWS / 64), 256, 0, stream>>>(
        aout_h, Wout_t, out, nullptr, nullptr, BROWS, DIM, INNER);
}